// Round 1
// baseline (1303.134 us; speedup 1.0000x reference)
//
#include <hip/hip_runtime.h>
#include <cstdint>

#define TPB 256

// ---------------------------------------------------------------------------
// EdgeGCN: 3x GCNConv (N=100k, 32->64->64->64) + per-edge MLP (136->64->32->1)
// Strategy: build CSR-by-target once per launch, gather-based aggregation
// (no float atomics), fp32 VALU everywhere (no fp32 MFMA on CDNA4).
// ---------------------------------------------------------------------------

__device__ __forceinline__ void fma_row64(float zi, const float* __restrict__ wrow,
                                          float* acc) {
  const float4* w4 = (const float4*)wrow;
#pragma unroll
  for (int j4 = 0; j4 < 16; ++j4) {
    float4 w = w4[j4];
    acc[4 * j4 + 0] = fmaf(zi, w.x, acc[4 * j4 + 0]);
    acc[4 * j4 + 1] = fmaf(zi, w.y, acc[4 * j4 + 1]);
    acc[4 * j4 + 2] = fmaf(zi, w.z, acc[4 * j4 + 2]);
    acc[4 * j4 + 3] = fmaf(zi, w.w, acc[4 * j4 + 3]);
  }
}

// --- index handling: detect int64 vs int32 edge_index --------------------
__global__ void detect_idx64(const int* __restrict__ ei, int* __restrict__ flag) {
  if (threadIdx.x == 0 && blockIdx.x == 0) {
    int o = 0;
    for (int k = 0; k < 32; ++k) o |= ei[2 * k + 1];  // high words if int64
    *flag = (o == 0) ? 1 : 0;
  }
}

__global__ __launch_bounds__(TPB) void normalize_idx(const int* __restrict__ ei,
                                                     const int* __restrict__ flag,
                                                     int* __restrict__ uu,
                                                     int* __restrict__ vv, int E) {
  int e = blockIdx.x * TPB + threadIdx.x;
  if (e >= E) return;
  if (*flag) {  // int64 little-endian: low word at 2*k
    uu[e] = ei[2 * (size_t)e];
    vv[e] = ei[2 * ((size_t)E + e)];
  } else {
    uu[e] = ei[e];
    vv[e] = ei[(size_t)E + e];
  }
}

// --- degree / CSR build ----------------------------------------------------
__global__ __launch_bounds__(TPB) void zero_ints(int* __restrict__ a,
                                                 int* __restrict__ b, int n) {
  int i = blockIdx.x * TPB + threadIdx.x;
  if (i < n) { a[i] = 0; b[i] = 0; }
}

__global__ __launch_bounds__(TPB) void count_deg(const int* __restrict__ vv,
                                                 int* __restrict__ cnt, int E) {
  int e = blockIdx.x * TPB + threadIdx.x;
  if (e < E) atomicAdd(&cnt[vv[e]], 1);
}

__global__ __launch_bounds__(TPB) void calc_dinv(const int* __restrict__ cnt,
                                                 float* __restrict__ dinv, int n) {
  int i = blockIdx.x * TPB + threadIdx.x;
  if (i < n) dinv[i] = rsqrtf((float)cnt[i] + 1.0f);  // +1 self-loop
}

// exclusive scan of cnt -> row_ptr, 1024 elems/block
__global__ __launch_bounds__(TPB) void scan1(const int* __restrict__ cnt,
                                             int* __restrict__ out,
                                             int* __restrict__ bsums, int n) {
  __shared__ int tmp[TPB];
  int tid = threadIdx.x;
  int base = blockIdx.x * 1024 + tid * 4;
  int v0 = 0, v1 = 0, v2 = 0, v3 = 0;
  if (base + 0 < n) v0 = cnt[base + 0];
  if (base + 1 < n) v1 = cnt[base + 1];
  if (base + 2 < n) v2 = cnt[base + 2];
  if (base + 3 < n) v3 = cnt[base + 3];
  int s = v0 + v1 + v2 + v3;
  tmp[tid] = s;
  __syncthreads();
  for (int off = 1; off < TPB; off <<= 1) {
    int x = (tid >= off) ? tmp[tid - off] : 0;
    __syncthreads();
    tmp[tid] += x;
    __syncthreads();
  }
  int excl = tmp[tid] - s;
  if (tid == TPB - 1) bsums[blockIdx.x] = tmp[TPB - 1];
  if (base + 0 < n) out[base + 0] = excl;
  if (base + 1 < n) out[base + 1] = excl + v0;
  if (base + 2 < n) out[base + 2] = excl + v0 + v1;
  if (base + 3 < n) out[base + 3] = excl + v0 + v1 + v2;
}

__global__ void scan2(int* __restrict__ bsums, int nb) {
  if (threadIdx.x == 0 && blockIdx.x == 0) {
    int run = 0;
    for (int i = 0; i < nb; ++i) { int t = bsums[i]; bsums[i] = run; run += t; }
  }
}

__global__ __launch_bounds__(TPB) void scan3(int* __restrict__ row_ptr,
                                             const int* __restrict__ bsums, int n,
                                             int total) {
  int i = blockIdx.x * TPB + threadIdx.x;
  if (i < n) row_ptr[i] += bsums[i >> 10];
  if (i == 0) row_ptr[n] = total;
}

__global__ __launch_bounds__(TPB) void fill_csr(const int* __restrict__ uu,
                                                const int* __restrict__ vv,
                                                const int* __restrict__ row_ptr,
                                                int* __restrict__ fill,
                                                const float* __restrict__ dinv,
                                                int* __restrict__ u_sorted,
                                                float* __restrict__ nrm, int E) {
  int e = blockIdx.x * TPB + threadIdx.x;
  if (e >= E) return;
  int u = uu[e], v = vv[e];
  int slot = row_ptr[v] + atomicAdd(&fill[v], 1);
  u_sorted[slot] = u;
  nrm[slot] = dinv[u] * dinv[v];
}

// --- GCN linear: B[node][0:64] = A[node][0:FIN] @ W ------------------------
template <int FIN>
__global__ __launch_bounds__(TPB) void lin_node(const float* __restrict__ A,
                                                const float* __restrict__ W,
                                                float* __restrict__ B, int n) {
  __shared__ __align__(16) float Ws[FIN * 64];
  int tid = threadIdx.x;
  for (int i = tid; i < FIN * 64; i += TPB) Ws[i] = W[i];
  __syncthreads();
  int node = blockIdx.x * TPB + tid;
  if (node >= n) return;
  const float4* a4 = (const float4*)(A + (size_t)node * FIN);
  float acc[64];
#pragma unroll
  for (int j = 0; j < 64; ++j) acc[j] = 0.f;
  for (int i4 = 0; i4 < FIN / 4; ++i4) {
    float4 z = a4[i4];
    fma_row64(z.x, &Ws[(4 * i4 + 0) * 64], acc);
    fma_row64(z.y, &Ws[(4 * i4 + 1) * 64], acc);
    fma_row64(z.z, &Ws[(4 * i4 + 2) * 64], acc);
    fma_row64(z.w, &Ws[(4 * i4 + 3) * 64], acc);
  }
  float4* b4 = (float4*)(B + (size_t)node * 64);
#pragma unroll
  for (int j4 = 0; j4 < 16; ++j4)
    b4[j4] = make_float4(acc[4 * j4 + 0], acc[4 * j4 + 1], acc[4 * j4 + 2],
                         acc[4 * j4 + 3]);
}

// --- aggregation: one wave per node, lane = feature ------------------------
__global__ __launch_bounds__(TPB) void aggregate(const float* __restrict__ B,
                                                 const int* __restrict__ row_ptr,
                                                 const int* __restrict__ u_sorted,
                                                 const float* __restrict__ nrm,
                                                 const float* __restrict__ dinv,
                                                 const float* __restrict__ bias,
                                                 float* __restrict__ A, int n) {
  int wid = (blockIdx.x * TPB + threadIdx.x) >> 6;  // node
  int lane = threadIdx.x & 63;                      // feature
  if (wid >= n) return;
  float dv = dinv[wid];
  float acc = B[(size_t)wid * 64 + lane] * dv * dv;  // self-loop
  int rs = row_ptr[wid], re = row_ptr[wid + 1];
  for (int j = rs; j < re; ++j) {
    int u = u_sorted[j];
    float w = nrm[j];
    acc = fmaf(B[(size_t)u * 64 + lane], w, acc);
  }
  A[(size_t)wid * 64 + lane] = fmaxf(acc + bias[lane], 0.f);
}

// --- edge MLP: one thread per edge ----------------------------------------
__global__ __launch_bounds__(TPB) void edge_mlp(
    const float* __restrict__ H, const int* __restrict__ uu,
    const int* __restrict__ vv, const float* __restrict__ EF,
    const float* __restrict__ Wm1, const float* __restrict__ bm1,
    const float* __restrict__ Wm2, const float* __restrict__ bm2,
    const float* __restrict__ Wm3, const float* __restrict__ bm3,
    float* __restrict__ out, int E) {
  __shared__ __align__(16) float W1s[136 * 64];
  __shared__ __align__(16) float W2s[64 * 32];
  __shared__ float b1s[64], b2s[32], W3s[32], b3s[1];
  int tid = threadIdx.x;
  for (int i = tid; i < 136 * 64; i += TPB) W1s[i] = Wm1[i];
  for (int i = tid; i < 64 * 32; i += TPB) W2s[i] = Wm2[i];
  if (tid < 64) b1s[tid] = bm1[tid];
  if (tid < 32) { b2s[tid] = bm2[tid]; W3s[tid] = Wm3[tid]; }
  if (tid == 0) b3s[0] = bm3[0];
  __syncthreads();

  int e = blockIdx.x * TPB + tid;
  if (e >= E) return;
  int u = uu[e], v = vv[e];
  const float4* hu = (const float4*)(H + (size_t)u * 64);
  const float4* hv = (const float4*)(H + (size_t)v * 64);

  float acc[64];
#pragma unroll
  for (int j = 0; j < 64; ++j) acc[j] = b1s[j];

#pragma unroll 2
  for (int i4 = 0; i4 < 16; ++i4) {
    float4 z = hu[i4];
    fma_row64(z.x, &W1s[(4 * i4 + 0) * 64], acc);
    fma_row64(z.y, &W1s[(4 * i4 + 1) * 64], acc);
    fma_row64(z.z, &W1s[(4 * i4 + 2) * 64], acc);
    fma_row64(z.w, &W1s[(4 * i4 + 3) * 64], acc);
  }
#pragma unroll 2
  for (int i4 = 0; i4 < 16; ++i4) {
    float4 z = hv[i4];
    fma_row64(z.x, &W1s[(64 + 4 * i4 + 0) * 64], acc);
    fma_row64(z.y, &W1s[(64 + 4 * i4 + 1) * 64], acc);
    fma_row64(z.z, &W1s[(64 + 4 * i4 + 2) * 64], acc);
    fma_row64(z.w, &W1s[(64 + 4 * i4 + 3) * 64], acc);
  }
  {
    const float4* ef4 = (const float4*)(EF + (size_t)e * 8);
    float4 z0 = ef4[0], z1 = ef4[1];
    fma_row64(z0.x, &W1s[128 * 64], acc);
    fma_row64(z0.y, &W1s[129 * 64], acc);
    fma_row64(z0.z, &W1s[130 * 64], acc);
    fma_row64(z0.w, &W1s[131 * 64], acc);
    fma_row64(z1.x, &W1s[132 * 64], acc);
    fma_row64(z1.y, &W1s[133 * 64], acc);
    fma_row64(z1.z, &W1s[134 * 64], acc);
    fma_row64(z1.w, &W1s[135 * 64], acc);
  }

  // layer 2: 64 -> 32 (relu on input of layer2 = relu(acc))
  float z2[32];
#pragma unroll
  for (int j = 0; j < 32; ++j) z2[j] = b2s[j];
#pragma unroll
  for (int i = 0; i < 64; ++i) {
    float zi = fmaxf(acc[i], 0.f);
    const float4* w4 = (const float4*)&W2s[i * 32];
#pragma unroll
    for (int j4 = 0; j4 < 8; ++j4) {
      float4 w = w4[j4];
      z2[4 * j4 + 0] = fmaf(zi, w.x, z2[4 * j4 + 0]);
      z2[4 * j4 + 1] = fmaf(zi, w.y, z2[4 * j4 + 1]);
      z2[4 * j4 + 2] = fmaf(zi, w.z, z2[4 * j4 + 2]);
      z2[4 * j4 + 3] = fmaf(zi, w.w, z2[4 * j4 + 3]);
    }
  }
  // layer 3: 32 -> 1
  float o = b3s[0];
#pragma unroll
  for (int i = 0; i < 32; ++i) o = fmaf(fmaxf(z2[i], 0.f), W3s[i], o);
  out[e] = o;
}

// ---------------------------------------------------------------------------
extern "C" void kernel_launch(void* const* d_in, const int* in_sizes, int n_in,
                              void* d_out, int out_size, void* d_ws, size_t ws_size,
                              hipStream_t stream) {
  const float* x   = (const float*)d_in[0];
  const int*   ei  = (const int*)d_in[1];
  const float* ef  = (const float*)d_in[2];
  const float* W0  = (const float*)d_in[3];
  const float* b0  = (const float*)d_in[4];
  const float* W1  = (const float*)d_in[5];
  const float* b1  = (const float*)d_in[6];
  const float* W2  = (const float*)d_in[7];
  const float* b2  = (const float*)d_in[8];
  const float* Wm1 = (const float*)d_in[9];
  const float* bm1 = (const float*)d_in[10];
  const float* Wm2 = (const float*)d_in[11];
  const float* bm2 = (const float*)d_in[12];
  const float* Wm3 = (const float*)d_in[13];
  const float* bm3 = (const float*)d_in[14];
  float* out = (float*)d_out;

  const int N = in_sizes[0] / 32;
  const int E = in_sizes[2] / 8;

  // workspace carve (256B aligned)
  char* p = (char*)d_ws;
  auto carve = [&](size_t bytes) {
    void* r = (void*)p;
    p += ((bytes + 255) / 256) * 256;
    return r;
  };
  int*   cnt      = (int*)carve((size_t)N * 4);
  int*   row_ptr  = (int*)carve((size_t)(N + 1) * 4);
  int*   fill     = (int*)carve((size_t)N * 4);
  int*   uu       = (int*)carve((size_t)E * 4);
  int*   vv       = (int*)carve((size_t)E * 4);
  int*   u_sorted = (int*)carve((size_t)E * 4);
  float* nrm      = (float*)carve((size_t)E * 4);
  float* dinv     = (float*)carve((size_t)N * 4);
  int*   bsums    = (int*)carve(4096);
  int*   flag     = (int*)carve(256);
  float* bufA     = (float*)carve((size_t)N * 64 * 4);
  float* bufB     = (float*)carve((size_t)N * 64 * 4);
  if ((size_t)(p - (char*)d_ws) > ws_size) return;  // ws too small: bail loudly

  const int EB = (E + TPB - 1) / TPB;
  const int NB = (N + TPB - 1) / TPB;
  const int SB = (N + 1023) / 1024;
  const int AB = (N + 3) / 4;  // 4 waves/block, wave per node

  zero_ints<<<NB, TPB, 0, stream>>>(cnt, fill, N);
  detect_idx64<<<1, 64, 0, stream>>>(ei, flag);
  normalize_idx<<<EB, TPB, 0, stream>>>(ei, flag, uu, vv, E);
  count_deg<<<EB, TPB, 0, stream>>>(vv, cnt, E);
  calc_dinv<<<NB, TPB, 0, stream>>>(cnt, dinv, N);
  scan1<<<SB, TPB, 0, stream>>>(cnt, row_ptr, bsums, N);
  scan2<<<1, 64, 0, stream>>>(bsums, SB);
  scan3<<<NB, TPB, 0, stream>>>(row_ptr, bsums, N, E);
  fill_csr<<<EB, TPB, 0, stream>>>(uu, vv, row_ptr, fill, dinv, u_sorted, nrm, E);

  // layer 0: x(N,32) -> bufA
  lin_node<32><<<NB, TPB, 0, stream>>>(x, W0, bufB, N);
  aggregate<<<AB, TPB, 0, stream>>>(bufB, row_ptr, u_sorted, nrm, dinv, b0, bufA, N);
  // layer 1
  lin_node<64><<<NB, TPB, 0, stream>>>(bufA, W1, bufB, N);
  aggregate<<<AB, TPB, 0, stream>>>(bufB, row_ptr, u_sorted, nrm, dinv, b1, bufA, N);
  // layer 2
  lin_node<64><<<NB, TPB, 0, stream>>>(bufA, W2, bufB, N);
  aggregate<<<AB, TPB, 0, stream>>>(bufB, row_ptr, u_sorted, nrm, dinv, b2, bufA, N);

  // edge MLP
  edge_mlp<<<EB, TPB, 0, stream>>>(bufA, uu, vv, ef, Wm1, bm1, Wm2, bm2, Wm3, bm3,
                                   out, E);
}

// Round 2
// 910.622 us; speedup vs baseline: 1.4310x; 1.4310x over previous
//
#include <hip/hip_runtime.h>
#include <cstdint>

#define TPB 256
#define TPBE 512

// ---------------------------------------------------------------------------
// EdgeGCN: 3x GCNConv (N=100k, 32->64->64->64) + per-edge MLP (136->64->32->1)
// R1: factor edge-MLP layer 1 through the concat (per-node precompute),
//     slim edge kernel LDS 44->10.5 KB for occupancy, fuse setup kernels.
// ---------------------------------------------------------------------------

__device__ __forceinline__ void fma_row64(float zi, const float* __restrict__ wrow,
                                          float* acc) {
  const float4* w4 = (const float4*)wrow;
#pragma unroll
  for (int j4 = 0; j4 < 16; ++j4) {
    float4 w = w4[j4];
    acc[4 * j4 + 0] = fmaf(zi, w.x, acc[4 * j4 + 0]);
    acc[4 * j4 + 1] = fmaf(zi, w.y, acc[4 * j4 + 1]);
    acc[4 * j4 + 2] = fmaf(zi, w.z, acc[4 * j4 + 2]);
    acc[4 * j4 + 3] = fmaf(zi, w.w, acc[4 * j4 + 3]);
  }
}

// --- zero cnt/fill + detect int64-vs-int32 edge_index ----------------------
__global__ __launch_bounds__(TPB) void prep(int* __restrict__ cnt,
                                            int* __restrict__ fill, int n,
                                            const int* __restrict__ ei,
                                            int* __restrict__ flag) {
  int i = blockIdx.x * TPB + threadIdx.x;
  if (i < n) { cnt[i] = 0; fill[i] = 0; }
  if (blockIdx.x == 0 && threadIdx.x == 0) {
    int o = 0;
    for (int k = 0; k < 32; ++k) o |= ei[2 * k + 1];  // high words if int64
    *flag = (o == 0) ? 1 : 0;
  }
}

// --- normalize indices to int32 + count in-degree --------------------------
__global__ __launch_bounds__(TPB) void normalize_count(const int* __restrict__ ei,
                                                       const int* __restrict__ flag,
                                                       int* __restrict__ uu,
                                                       int* __restrict__ vv,
                                                       int* __restrict__ cnt, int E) {
  int e = blockIdx.x * TPB + threadIdx.x;
  if (e >= E) return;
  int u, v;
  if (*flag) {  // int64 little-endian: low word at 2*k
    u = ei[2 * (size_t)e];
    v = ei[2 * ((size_t)E + e)];
  } else {
    u = ei[e];
    v = ei[(size_t)E + e];
  }
  uu[e] = u;
  vv[e] = v;
  atomicAdd(&cnt[v], 1);
}

// exclusive scan of cnt -> row_ptr (1024 elems/block) + dinv = rsqrt(cnt+1)
__global__ __launch_bounds__(TPB) void scan1(const int* __restrict__ cnt,
                                             int* __restrict__ out,
                                             int* __restrict__ bsums,
                                             float* __restrict__ dinv, int n) {
  __shared__ int tmp[TPB];
  int tid = threadIdx.x;
  int base = blockIdx.x * 1024 + tid * 4;
  int v0 = 0, v1 = 0, v2 = 0, v3 = 0;
  if (base + 0 < n) v0 = cnt[base + 0];
  if (base + 1 < n) v1 = cnt[base + 1];
  if (base + 2 < n) v2 = cnt[base + 2];
  if (base + 3 < n) v3 = cnt[base + 3];
  if (base + 0 < n) dinv[base + 0] = rsqrtf((float)v0 + 1.0f);
  if (base + 1 < n) dinv[base + 1] = rsqrtf((float)v1 + 1.0f);
  if (base + 2 < n) dinv[base + 2] = rsqrtf((float)v2 + 1.0f);
  if (base + 3 < n) dinv[base + 3] = rsqrtf((float)v3 + 1.0f);
  int s = v0 + v1 + v2 + v3;
  tmp[tid] = s;
  __syncthreads();
  for (int off = 1; off < TPB; off <<= 1) {
    int x = (tid >= off) ? tmp[tid - off] : 0;
    __syncthreads();
    tmp[tid] += x;
    __syncthreads();
  }
  int excl = tmp[tid] - s;
  if (tid == TPB - 1) bsums[blockIdx.x] = tmp[TPB - 1];
  if (base + 0 < n) out[base + 0] = excl;
  if (base + 1 < n) out[base + 1] = excl + v0;
  if (base + 2 < n) out[base + 2] = excl + v0 + v1;
  if (base + 3 < n) out[base + 3] = excl + v0 + v1 + v2;
}

__global__ void scan2(int* __restrict__ bsums, int nb) {
  if (threadIdx.x == 0 && blockIdx.x == 0) {
    int run = 0;
    for (int i = 0; i < nb; ++i) { int t = bsums[i]; bsums[i] = run; run += t; }
  }
}

__global__ __launch_bounds__(TPB) void scan3(int* __restrict__ row_ptr,
                                             const int* __restrict__ bsums, int n,
                                             int total) {
  int i = blockIdx.x * TPB + threadIdx.x;
  if (i < n) row_ptr[i] += bsums[i >> 10];
  if (i == 0) row_ptr[n] = total;
}

__global__ __launch_bounds__(TPB) void fill_csr(const int* __restrict__ uu,
                                                const int* __restrict__ vv,
                                                const int* __restrict__ row_ptr,
                                                int* __restrict__ fill,
                                                const float* __restrict__ dinv,
                                                int* __restrict__ u_sorted,
                                                float* __restrict__ nrm, int E) {
  int e = blockIdx.x * TPB + threadIdx.x;
  if (e >= E) return;
  int u = uu[e], v = vv[e];
  int slot = row_ptr[v] + atomicAdd(&fill[v], 1);
  u_sorted[slot] = u;
  nrm[slot] = dinv[u] * dinv[v];
}

// --- node linear: B[node][0:64] = A[node][0:FIN] @ W -----------------------
template <int FIN>
__global__ __launch_bounds__(TPB) void lin_node(const float* __restrict__ A,
                                                const float* __restrict__ W,
                                                float* __restrict__ B, int n) {
  __shared__ __align__(16) float Ws[FIN * 64];
  int tid = threadIdx.x;
  for (int i = tid; i < FIN * 64; i += TPB) Ws[i] = W[i];
  __syncthreads();
  int node = blockIdx.x * TPB + tid;
  if (node >= n) return;
  const float4* a4 = (const float4*)(A + (size_t)node * FIN);
  float acc[64];
#pragma unroll
  for (int j = 0; j < 64; ++j) acc[j] = 0.f;
  for (int i4 = 0; i4 < FIN / 4; ++i4) {
    float4 z = a4[i4];
    fma_row64(z.x, &Ws[(4 * i4 + 0) * 64], acc);
    fma_row64(z.y, &Ws[(4 * i4 + 1) * 64], acc);
    fma_row64(z.z, &Ws[(4 * i4 + 2) * 64], acc);
    fma_row64(z.w, &Ws[(4 * i4 + 3) * 64], acc);
  }
  float4* b4 = (float4*)(B + (size_t)node * 64);
#pragma unroll
  for (int j4 = 0; j4 < 16; ++j4)
    b4[j4] = make_float4(acc[4 * j4 + 0], acc[4 * j4 + 1], acc[4 * j4 + 2],
                         acc[4 * j4 + 3]);
}

// --- aggregation: one wave per node, lane = feature ------------------------
__global__ __launch_bounds__(TPB) void aggregate(const float* __restrict__ B,
                                                 const int* __restrict__ row_ptr,
                                                 const int* __restrict__ u_sorted,
                                                 const float* __restrict__ nrm,
                                                 const float* __restrict__ dinv,
                                                 const float* __restrict__ bias,
                                                 float* __restrict__ A, int n) {
  int wid = (blockIdx.x * TPB + threadIdx.x) >> 6;  // node
  int lane = threadIdx.x & 63;                      // feature
  if (wid >= n) return;
  float dv = dinv[wid];
  float acc0 = B[(size_t)wid * 64 + lane] * dv * dv;  // self-loop
  float acc1 = 0.f;
  int rs = row_ptr[wid], re = row_ptr[wid + 1];
  int j = rs;
  for (; j + 1 < re; j += 2) {
    int u0 = u_sorted[j], u1 = u_sorted[j + 1];
    float w0 = nrm[j], w1 = nrm[j + 1];
    acc0 = fmaf(B[(size_t)u0 * 64 + lane], w0, acc0);
    acc1 = fmaf(B[(size_t)u1 * 64 + lane], w1, acc1);
  }
  if (j < re) {
    int u0 = u_sorted[j];
    acc0 = fmaf(B[(size_t)u0 * 64 + lane], nrm[j], acc0);
  }
  A[(size_t)wid * 64 + lane] = fmaxf(acc0 + acc1 + bias[lane], 0.f);
}

// --- edge MLP (factored layer 1): one thread per edge ----------------------
// acc = apre[u] + bpre[v] + ef @ Wm1[128:136] + bm1; relu; 64->32; relu; ->1
__global__ __launch_bounds__(TPBE) void edge_mlp(
    const float* __restrict__ apre, const float* __restrict__ bpre,
    const int* __restrict__ uu, const int* __restrict__ vv,
    const float* __restrict__ EF, const float* __restrict__ W1e,  // Wm1+128*64
    const float* __restrict__ bm1, const float* __restrict__ Wm2,
    const float* __restrict__ bm2, const float* __restrict__ Wm3,
    const float* __restrict__ bm3, float* __restrict__ out, int E) {
  __shared__ __align__(16) float W1s[8 * 64];   // edge-feature rows of Wm1
  __shared__ __align__(16) float W2s[64 * 32];
  __shared__ float b1s[64], b2s[32], W3s[32], b3s[1];
  int tid = threadIdx.x;
  for (int i = tid; i < 8 * 64; i += TPBE) W1s[i] = W1e[i];
  for (int i = tid; i < 64 * 32; i += TPBE) W2s[i] = Wm2[i];
  if (tid < 64) b1s[tid] = bm1[tid];
  if (tid < 32) { b2s[tid] = bm2[tid]; W3s[tid] = Wm3[tid]; }
  if (tid == 0) b3s[0] = bm3[0];
  __syncthreads();

  int e = blockIdx.x * TPBE + tid;
  if (e >= E) return;
  int u = uu[e], v = vv[e];
  const float4* a4 = (const float4*)(apre + (size_t)u * 64);
  const float4* b4 = (const float4*)(bpre + (size_t)v * 64);
  const float4* ef4 = (const float4*)(EF + (size_t)e * 8);

  // layer 1: edge-feature part first (hides gather latency of a4/b4)
  float4 z0 = ef4[0], z1 = ef4[1];
  float acc[64];
#pragma unroll
  for (int j = 0; j < 64; ++j) acc[j] = b1s[j];
  fma_row64(z0.x, &W1s[0 * 64], acc);
  fma_row64(z0.y, &W1s[1 * 64], acc);
  fma_row64(z0.z, &W1s[2 * 64], acc);
  fma_row64(z0.w, &W1s[3 * 64], acc);
  fma_row64(z1.x, &W1s[4 * 64], acc);
  fma_row64(z1.y, &W1s[5 * 64], acc);
  fma_row64(z1.z, &W1s[6 * 64], acc);
  fma_row64(z1.w, &W1s[7 * 64], acc);

  // add node precomputes (gathered rows)
#pragma unroll
  for (int i4 = 0; i4 < 16; ++i4) {
    float4 za = a4[i4];
    float4 zb = b4[i4];
    acc[4 * i4 + 0] += za.x + zb.x;
    acc[4 * i4 + 1] += za.y + zb.y;
    acc[4 * i4 + 2] += za.z + zb.z;
    acc[4 * i4 + 3] += za.w + zb.w;
  }

  // layer 2: 64 -> 32, relu on inputs
  float z2[32];
#pragma unroll
  for (int j = 0; j < 32; ++j) z2[j] = b2s[j];
#pragma unroll
  for (int i = 0; i < 64; ++i) {
    float zi = fmaxf(acc[i], 0.f);
    const float4* w4 = (const float4*)&W2s[i * 32];
#pragma unroll
    for (int j4 = 0; j4 < 8; ++j4) {
      float4 w = w4[j4];
      z2[4 * j4 + 0] = fmaf(zi, w.x, z2[4 * j4 + 0]);
      z2[4 * j4 + 1] = fmaf(zi, w.y, z2[4 * j4 + 1]);
      z2[4 * j4 + 2] = fmaf(zi, w.z, z2[4 * j4 + 2]);
      z2[4 * j4 + 3] = fmaf(zi, w.w, z2[4 * j4 + 3]);
    }
  }
  // layer 3: 32 -> 1
  float o = b3s[0];
#pragma unroll
  for (int i = 0; i < 32; ++i) o = fmaf(fmaxf(z2[i], 0.f), W3s[i], o);
  out[e] = o;
}

// ---------------------------------------------------------------------------
extern "C" void kernel_launch(void* const* d_in, const int* in_sizes, int n_in,
                              void* d_out, int out_size, void* d_ws, size_t ws_size,
                              hipStream_t stream) {
  const float* x   = (const float*)d_in[0];
  const int*   ei  = (const int*)d_in[1];
  const float* ef  = (const float*)d_in[2];
  const float* W0  = (const float*)d_in[3];
  const float* b0  = (const float*)d_in[4];
  const float* W1  = (const float*)d_in[5];
  const float* b1  = (const float*)d_in[6];
  const float* W2  = (const float*)d_in[7];
  const float* b2  = (const float*)d_in[8];
  const float* Wm1 = (const float*)d_in[9];
  const float* bm1 = (const float*)d_in[10];
  const float* Wm2 = (const float*)d_in[11];
  const float* bm2 = (const float*)d_in[12];
  const float* Wm3 = (const float*)d_in[13];
  const float* bm3 = (const float*)d_in[14];
  float* out = (float*)d_out;

  const int N = in_sizes[0] / 32;
  const int E = in_sizes[2] / 8;

  // workspace carve (256B aligned)
  char* p = (char*)d_ws;
  auto carve = [&](size_t bytes) {
    void* r = (void*)p;
    p += ((bytes + 255) / 256) * 256;
    return r;
  };
  int*   cnt      = (int*)carve((size_t)N * 4);
  int*   row_ptr  = (int*)carve((size_t)(N + 1) * 4);
  int*   fill     = (int*)carve((size_t)N * 4);
  int*   uu       = (int*)carve((size_t)E * 4);
  int*   vv       = (int*)carve((size_t)E * 4);
  int*   u_sorted = (int*)carve((size_t)E * 4);
  float* nrm      = (float*)carve((size_t)E * 4);
  float* dinv     = (float*)carve((size_t)N * 4);
  int*   bsums    = (int*)carve(4096);
  int*   flag     = (int*)carve(256);
  float* bufA     = (float*)carve((size_t)N * 64 * 4);  // H (node features)
  float* bufB     = (float*)carve((size_t)N * 64 * 4);  // scratch / apre
  float* bpre     = (float*)carve((size_t)N * 64 * 4);  // bpre
  if ((size_t)(p - (char*)d_ws) > ws_size) return;  // ws too small: bail loudly

  const int EB = (E + TPB - 1) / TPB;
  const int EB2 = (E + TPBE - 1) / TPBE;
  const int NB = (N + TPB - 1) / TPB;
  const int SB = (N + 1023) / 1024;
  const int AB = (N + 3) / 4;  // 4 waves/block, wave per node

  prep<<<NB, TPB, 0, stream>>>(cnt, fill, N, ei, flag);
  normalize_count<<<EB, TPB, 0, stream>>>(ei, flag, uu, vv, cnt, E);
  scan1<<<SB, TPB, 0, stream>>>(cnt, row_ptr, bsums, dinv, N);
  scan2<<<1, 64, 0, stream>>>(bsums, SB);
  scan3<<<NB, TPB, 0, stream>>>(row_ptr, bsums, N, E);
  fill_csr<<<EB, TPB, 0, stream>>>(uu, vv, row_ptr, fill, dinv, u_sorted, nrm, E);

  // GCN layer 0: x(N,32) -> bufA
  lin_node<32><<<NB, TPB, 0, stream>>>(x, W0, bufB, N);
  aggregate<<<AB, TPB, 0, stream>>>(bufB, row_ptr, u_sorted, nrm, dinv, b0, bufA, N);
  // layer 1
  lin_node<64><<<NB, TPB, 0, stream>>>(bufA, W1, bufB, N);
  aggregate<<<AB, TPB, 0, stream>>>(bufB, row_ptr, u_sorted, nrm, dinv, b1, bufA, N);
  // layer 2
  lin_node<64><<<NB, TPB, 0, stream>>>(bufA, W2, bufB, N);
  aggregate<<<AB, TPB, 0, stream>>>(bufB, row_ptr, u_sorted, nrm, dinv, b2, bufA, N);

  // edge-MLP layer-1 factorization: apre = H@Wm1[0:64], bpre = H@Wm1[64:128]
  lin_node<64><<<NB, TPB, 0, stream>>>(bufA, Wm1, bufB, N);             // apre
  lin_node<64><<<NB, TPB, 0, stream>>>(bufA, Wm1 + 64 * 64, bpre, N);   // bpre

  // edge MLP
  edge_mlp<<<EB2, TPBE, 0, stream>>>(bufB, bpre, uu, vv, ef, Wm1 + 128 * 64, bm1,
                                     Wm2, bm2, Wm3, bm3, out, E);
}

// Round 3
// 774.878 us; speedup vs baseline: 1.6817x; 1.1752x over previous
//
#include <hip/hip_runtime.h>
#include <cstdint>

#define TPB 256
#define TPBE 512

// ---------------------------------------------------------------------------
// EdgeGCN: 3x GCNConv (N=100k, 32->64->64->64) + per-edge MLP (136->64->32->1)
// R3: CSR-ordered edge MLP (bpre[v] becomes broadcast/L1-hit), shuffle-
//     broadcast aggregate with 4-deep gather ILP, fused apre/bpre kernel.
// ---------------------------------------------------------------------------

__device__ __forceinline__ void fma_row64(float zi, const float* __restrict__ wrow,
                                          float* acc) {
  const float4* w4 = (const float4*)wrow;
#pragma unroll
  for (int j4 = 0; j4 < 16; ++j4) {
    float4 w = w4[j4];
    acc[4 * j4 + 0] = fmaf(zi, w.x, acc[4 * j4 + 0]);
    acc[4 * j4 + 1] = fmaf(zi, w.y, acc[4 * j4 + 1]);
    acc[4 * j4 + 2] = fmaf(zi, w.z, acc[4 * j4 + 2]);
    acc[4 * j4 + 3] = fmaf(zi, w.w, acc[4 * j4 + 3]);
  }
}

// --- zero cnt/fill + detect int64-vs-int32 edge_index ----------------------
__global__ __launch_bounds__(TPB) void prep(int* __restrict__ cnt,
                                            int* __restrict__ fill, int n,
                                            const int* __restrict__ ei,
                                            int* __restrict__ flag) {
  int i = blockIdx.x * TPB + threadIdx.x;
  if (i < n) { cnt[i] = 0; fill[i] = 0; }
  if (blockIdx.x == 0 && threadIdx.x == 0) {
    int o = 0;
    for (int k = 0; k < 32; ++k) o |= ei[2 * k + 1];  // high words if int64
    *flag = (o == 0) ? 1 : 0;
  }
}

// --- normalize indices to int32 + count in-degree --------------------------
__global__ __launch_bounds__(TPB) void normalize_count(const int* __restrict__ ei,
                                                       const int* __restrict__ flag,
                                                       int* __restrict__ uu,
                                                       int* __restrict__ vv,
                                                       int* __restrict__ cnt, int E) {
  int e = blockIdx.x * TPB + threadIdx.x;
  if (e >= E) return;
  int u, v;
  if (*flag) {  // int64 little-endian: low word at 2*k
    u = ei[2 * (size_t)e];
    v = ei[2 * ((size_t)E + e)];
  } else {
    u = ei[e];
    v = ei[(size_t)E + e];
  }
  uu[e] = u;
  vv[e] = v;
  atomicAdd(&cnt[v], 1);
}

// exclusive scan of cnt -> row_ptr (1024 elems/block) + dinv = rsqrt(cnt+1)
__global__ __launch_bounds__(TPB) void scan1(const int* __restrict__ cnt,
                                             int* __restrict__ out,
                                             int* __restrict__ bsums,
                                             float* __restrict__ dinv, int n) {
  __shared__ int tmp[TPB];
  int tid = threadIdx.x;
  int base = blockIdx.x * 1024 + tid * 4;
  int v0 = 0, v1 = 0, v2 = 0, v3 = 0;
  if (base + 0 < n) v0 = cnt[base + 0];
  if (base + 1 < n) v1 = cnt[base + 1];
  if (base + 2 < n) v2 = cnt[base + 2];
  if (base + 3 < n) v3 = cnt[base + 3];
  if (base + 0 < n) dinv[base + 0] = rsqrtf((float)v0 + 1.0f);
  if (base + 1 < n) dinv[base + 1] = rsqrtf((float)v1 + 1.0f);
  if (base + 2 < n) dinv[base + 2] = rsqrtf((float)v2 + 1.0f);
  if (base + 3 < n) dinv[base + 3] = rsqrtf((float)v3 + 1.0f);
  int s = v0 + v1 + v2 + v3;
  tmp[tid] = s;
  __syncthreads();
  for (int off = 1; off < TPB; off <<= 1) {
    int x = (tid >= off) ? tmp[tid - off] : 0;
    __syncthreads();
    tmp[tid] += x;
    __syncthreads();
  }
  int excl = tmp[tid] - s;
  if (tid == TPB - 1) bsums[blockIdx.x] = tmp[TPB - 1];
  if (base + 0 < n) out[base + 0] = excl;
  if (base + 1 < n) out[base + 1] = excl + v0;
  if (base + 2 < n) out[base + 2] = excl + v0 + v1;
  if (base + 3 < n) out[base + 3] = excl + v0 + v1 + v2;
}

__global__ void scan2(int* __restrict__ bsums, int nb) {
  if (threadIdx.x == 0 && blockIdx.x == 0) {
    int run = 0;
    for (int i = 0; i < nb; ++i) { int t = bsums[i]; bsums[i] = run; run += t; }
  }
}

__global__ __launch_bounds__(TPB) void scan3(int* __restrict__ row_ptr,
                                             const int* __restrict__ bsums, int n,
                                             int total) {
  int i = blockIdx.x * TPB + threadIdx.x;
  if (i < n) row_ptr[i] += bsums[i >> 10];
  if (i == 0) row_ptr[n] = total;
}

// --- CSR fill: also record v and original edge id per slot -----------------
__global__ __launch_bounds__(TPB) void fill_csr(const int* __restrict__ uu,
                                                const int* __restrict__ vv,
                                                const int* __restrict__ row_ptr,
                                                int* __restrict__ fill,
                                                const float* __restrict__ dinv,
                                                int* __restrict__ u_sorted,
                                                int* __restrict__ v_sorted,
                                                int* __restrict__ e_orig,
                                                float* __restrict__ nrm, int E) {
  int e = blockIdx.x * TPB + threadIdx.x;
  if (e >= E) return;
  int u = uu[e], v = vv[e];
  int slot = row_ptr[v] + atomicAdd(&fill[v], 1);
  u_sorted[slot] = u;
  v_sorted[slot] = v;
  e_orig[slot] = e;
  nrm[slot] = dinv[u] * dinv[v];
}

// --- node linear: B[node][0:64] = A[node][0:FIN] @ W -----------------------
template <int FIN>
__global__ __launch_bounds__(TPB) void lin_node(const float* __restrict__ A,
                                                const float* __restrict__ W,
                                                float* __restrict__ B, int n) {
  __shared__ __align__(16) float Ws[FIN * 64];
  int tid = threadIdx.x;
  for (int i = tid; i < FIN * 64; i += TPB) Ws[i] = W[i];
  __syncthreads();
  int node = blockIdx.x * TPB + tid;
  if (node >= n) return;
  const float4* a4 = (const float4*)(A + (size_t)node * FIN);
  float acc[64];
#pragma unroll
  for (int j = 0; j < 64; ++j) acc[j] = 0.f;
  for (int i4 = 0; i4 < FIN / 4; ++i4) {
    float4 z = a4[i4];
    fma_row64(z.x, &Ws[(4 * i4 + 0) * 64], acc);
    fma_row64(z.y, &Ws[(4 * i4 + 1) * 64], acc);
    fma_row64(z.z, &Ws[(4 * i4 + 2) * 64], acc);
    fma_row64(z.w, &Ws[(4 * i4 + 3) * 64], acc);
  }
  float4* b4 = (float4*)(B + (size_t)node * 64);
#pragma unroll
  for (int j4 = 0; j4 < 16; ++j4)
    b4[j4] = make_float4(acc[4 * j4 + 0], acc[4 * j4 + 1], acc[4 * j4 + 2],
                         acc[4 * j4 + 3]);
}

// --- fused apre/bpre: apre = A@W[0:64], bpre = A@W[64:128] -----------------
__global__ __launch_bounds__(TPB) void lin_ab(const float* __restrict__ A,
                                              const float* __restrict__ W,
                                              float* __restrict__ apre,
                                              float* __restrict__ bpre, int n) {
  __shared__ __align__(16) float Ws[128 * 64];  // 32 KB
  int tid = threadIdx.x;
  for (int i = tid; i < 128 * 64; i += TPB) Ws[i] = W[i];
  __syncthreads();
  int node = blockIdx.x * TPB + tid;
  if (node >= n) return;
  const float4* a4 = (const float4*)(A + (size_t)node * 64);
  float acc[64];
#pragma unroll
  for (int j = 0; j < 64; ++j) acc[j] = 0.f;
  for (int i4 = 0; i4 < 16; ++i4) {
    float4 z = a4[i4];
    fma_row64(z.x, &Ws[(4 * i4 + 0) * 64], acc);
    fma_row64(z.y, &Ws[(4 * i4 + 1) * 64], acc);
    fma_row64(z.z, &Ws[(4 * i4 + 2) * 64], acc);
    fma_row64(z.w, &Ws[(4 * i4 + 3) * 64], acc);
  }
  float4* o4 = (float4*)(apre + (size_t)node * 64);
#pragma unroll
  for (int j4 = 0; j4 < 16; ++j4)
    o4[j4] = make_float4(acc[4 * j4 + 0], acc[4 * j4 + 1], acc[4 * j4 + 2],
                         acc[4 * j4 + 3]);
#pragma unroll
  for (int j = 0; j < 64; ++j) acc[j] = 0.f;
  for (int i4 = 0; i4 < 16; ++i4) {
    float4 z = a4[i4];  // L1-hot reread
    fma_row64(z.x, &Ws[(64 + 4 * i4 + 0) * 64], acc);
    fma_row64(z.y, &Ws[(64 + 4 * i4 + 1) * 64], acc);
    fma_row64(z.z, &Ws[(64 + 4 * i4 + 2) * 64], acc);
    fma_row64(z.w, &Ws[(64 + 4 * i4 + 3) * 64], acc);
  }
  o4 = (float4*)(bpre + (size_t)node * 64);
#pragma unroll
  for (int j4 = 0; j4 < 16; ++j4)
    o4[j4] = make_float4(acc[4 * j4 + 0], acc[4 * j4 + 1], acc[4 * j4 + 2],
                         acc[4 * j4 + 3]);
}

// --- aggregation: wave per node; coalesced index load + shfl broadcast -----
__global__ __launch_bounds__(TPB) void aggregate(const float* __restrict__ B,
                                                 const int* __restrict__ row_ptr,
                                                 const int* __restrict__ u_sorted,
                                                 const float* __restrict__ nrm,
                                                 const float* __restrict__ dinv,
                                                 const float* __restrict__ bias,
                                                 float* __restrict__ A, int n) {
  int wid = (blockIdx.x * TPB + threadIdx.x) >> 6;  // node
  int lane = threadIdx.x & 63;                      // feature
  if (wid >= n) return;
  float dv = dinv[wid];
  float acc0 = B[(size_t)wid * 64 + lane] * dv * dv;  // self-loop
  float acc1 = 0.f, acc2 = 0.f, acc3 = 0.f;
  int rs = row_ptr[wid], re = row_ptr[wid + 1];
  for (int base = rs; base < re; base += 64) {
    int m = re - base;
    if (m > 64) m = 64;
    int uj = 0;
    float wj = 0.f;
    if (lane < m) { uj = u_sorted[base + lane]; wj = nrm[base + lane]; }
    int k = 0;
    for (; k + 3 < m; k += 4) {
      int u0 = __shfl(uj, k), u1 = __shfl(uj, k + 1);
      int u2 = __shfl(uj, k + 2), u3 = __shfl(uj, k + 3);
      float w0 = __shfl(wj, k), w1 = __shfl(wj, k + 1);
      float w2 = __shfl(wj, k + 2), w3 = __shfl(wj, k + 3);
      acc0 = fmaf(B[(size_t)u0 * 64 + lane], w0, acc0);
      acc1 = fmaf(B[(size_t)u1 * 64 + lane], w1, acc1);
      acc2 = fmaf(B[(size_t)u2 * 64 + lane], w2, acc2);
      acc3 = fmaf(B[(size_t)u3 * 64 + lane], w3, acc3);
    }
    for (; k < m; ++k) {
      int u0 = __shfl(uj, k);
      float w0 = __shfl(wj, k);
      acc0 = fmaf(B[(size_t)u0 * 64 + lane], w0, acc0);
    }
  }
  A[(size_t)wid * 64 + lane] =
      fmaxf((acc0 + acc1) + (acc2 + acc3) + bias[lane], 0.f);
}

// --- edge MLP, CSR order: thread t <-> CSR slot t --------------------------
// acc = apre[u] + bpre[v] + ef[e] @ Wm1[128:136] + bm1; relu; 64->32; relu; ->1
__global__ __launch_bounds__(TPBE) void edge_mlp(
    const float* __restrict__ apre, const float* __restrict__ bpre,
    const int* __restrict__ u_sorted, const int* __restrict__ v_sorted,
    const int* __restrict__ e_orig, const float* __restrict__ EF,
    const float* __restrict__ W1e,  // Wm1 + 128*64
    const float* __restrict__ bm1, const float* __restrict__ Wm2,
    const float* __restrict__ bm2, const float* __restrict__ Wm3,
    const float* __restrict__ bm3, float* __restrict__ out, int E) {
  __shared__ __align__(16) float W1s[8 * 64];   // edge-feature rows of Wm1
  __shared__ __align__(16) float W2s[64 * 32];
  __shared__ float b1s[64], b2s[32], W3s[32], b3s[1];
  int tid = threadIdx.x;
  for (int i = tid; i < 8 * 64; i += TPBE) W1s[i] = W1e[i];
  for (int i = tid; i < 64 * 32; i += TPBE) W2s[i] = Wm2[i];
  if (tid < 64) b1s[tid] = bm1[tid];
  if (tid < 32) { b2s[tid] = bm2[tid]; W3s[tid] = Wm3[tid]; }
  if (tid == 0) b3s[0] = bm3[0];
  __syncthreads();

  int t = blockIdx.x * TPBE + tid;
  if (t >= E) return;
  int u = u_sorted[t], v = v_sorted[t], e = e_orig[t];
  const float4* a4 = (const float4*)(apre + (size_t)u * 64);
  const float4* b4 = (const float4*)(bpre + (size_t)v * 64);  // wave-shared row
  const float4* ef4 = (const float4*)(EF + (size_t)e * 8);

  // layer 1: edge-feature part first (a4/b4 gathers fly underneath)
  float4 z0 = ef4[0], z1 = ef4[1];
  float acc[64];
#pragma unroll
  for (int j = 0; j < 64; ++j) acc[j] = b1s[j];
  fma_row64(z0.x, &W1s[0 * 64], acc);
  fma_row64(z0.y, &W1s[1 * 64], acc);
  fma_row64(z0.z, &W1s[2 * 64], acc);
  fma_row64(z0.w, &W1s[3 * 64], acc);
  fma_row64(z1.x, &W1s[4 * 64], acc);
  fma_row64(z1.y, &W1s[5 * 64], acc);
  fma_row64(z1.z, &W1s[6 * 64], acc);
  fma_row64(z1.w, &W1s[7 * 64], acc);

#pragma unroll
  for (int i4 = 0; i4 < 16; ++i4) {
    float4 za = a4[i4];
    float4 zb = b4[i4];
    acc[4 * i4 + 0] += za.x + zb.x;
    acc[4 * i4 + 1] += za.y + zb.y;
    acc[4 * i4 + 2] += za.z + zb.z;
    acc[4 * i4 + 3] += za.w + zb.w;
  }

  // layer 2: 64 -> 32, relu on inputs
  float z2[32];
#pragma unroll
  for (int j = 0; j < 32; ++j) z2[j] = b2s[j];
#pragma unroll
  for (int i = 0; i < 64; ++i) {
    float zi = fmaxf(acc[i], 0.f);
    const float4* w4 = (const float4*)&W2s[i * 32];
#pragma unroll
    for (int j4 = 0; j4 < 8; ++j4) {
      float4 w = w4[j4];
      z2[4 * j4 + 0] = fmaf(zi, w.x, z2[4 * j4 + 0]);
      z2[4 * j4 + 1] = fmaf(zi, w.y, z2[4 * j4 + 1]);
      z2[4 * j4 + 2] = fmaf(zi, w.z, z2[4 * j4 + 2]);
      z2[4 * j4 + 3] = fmaf(zi, w.w, z2[4 * j4 + 3]);
    }
  }
  // layer 3: 32 -> 1
  float o = b3s[0];
#pragma unroll
  for (int i = 0; i < 32; ++i) o = fmaf(fmaxf(z2[i], 0.f), W3s[i], o);
  out[e] = o;
}

// ---------------------------------------------------------------------------
extern "C" void kernel_launch(void* const* d_in, const int* in_sizes, int n_in,
                              void* d_out, int out_size, void* d_ws, size_t ws_size,
                              hipStream_t stream) {
  const float* x   = (const float*)d_in[0];
  const int*   ei  = (const int*)d_in[1];
  const float* ef  = (const float*)d_in[2];
  const float* W0  = (const float*)d_in[3];
  const float* b0  = (const float*)d_in[4];
  const float* W1  = (const float*)d_in[5];
  const float* b1  = (const float*)d_in[6];
  const float* W2  = (const float*)d_in[7];
  const float* b2  = (const float*)d_in[8];
  const float* Wm1 = (const float*)d_in[9];
  const float* bm1 = (const float*)d_in[10];
  const float* Wm2 = (const float*)d_in[11];
  const float* bm2 = (const float*)d_in[12];
  const float* Wm3 = (const float*)d_in[13];
  const float* bm3 = (const float*)d_in[14];
  float* out = (float*)d_out;

  const int N = in_sizes[0] / 32;
  const int E = in_sizes[2] / 8;

  // workspace carve (256B aligned)
  char* p = (char*)d_ws;
  auto carve = [&](size_t bytes) {
    void* r = (void*)p;
    p += ((bytes + 255) / 256) * 256;
    return r;
  };
  int*   cnt      = (int*)carve((size_t)N * 4);
  int*   row_ptr  = (int*)carve((size_t)(N + 1) * 4);
  int*   fill     = (int*)carve((size_t)N * 4);
  float* dinv     = (float*)carve((size_t)N * 4);
  int*   bsums    = (int*)carve(4096);
  int*   flag     = (int*)carve(256);
  int*   u_sorted = (int*)carve((size_t)E * 4);
  int*   v_sorted = (int*)carve((size_t)E * 4);
  int*   e_orig   = (int*)carve((size_t)E * 4);
  float* nrm      = (float*)carve((size_t)E * 4);
  float* bufB     = (float*)carve((size_t)N * 64 * 4);  // scratch / apre
  float* bpre     = (float*)carve((size_t)N * 64 * 4);  // bpre
  float* bufA     = (float*)carve((size_t)N * 64 * 4);  // H; head doubles as uu/vv
  if ((size_t)(p - (char*)d_ws) > ws_size) return;  // ws too small: bail loudly

  // uu/vv alias the head of bufA: dead after fill_csr, before bufA is written
  int* uu = (int*)bufA;
  int* vv = uu + E;

  const int EB = (E + TPB - 1) / TPB;
  const int EB2 = (E + TPBE - 1) / TPBE;
  const int NB = (N + TPB - 1) / TPB;
  const int SB = (N + 1023) / 1024;
  const int AB = (N + 3) / 4;  // 4 waves/block, wave per node

  prep<<<NB, TPB, 0, stream>>>(cnt, fill, N, ei, flag);
  normalize_count<<<EB, TPB, 0, stream>>>(ei, flag, uu, vv, cnt, E);
  scan1<<<SB, TPB, 0, stream>>>(cnt, row_ptr, bsums, dinv, N);
  scan2<<<1, 64, 0, stream>>>(bsums, SB);
  scan3<<<NB, TPB, 0, stream>>>(row_ptr, bsums, N, E);
  fill_csr<<<EB, TPB, 0, stream>>>(uu, vv, row_ptr, fill, dinv, u_sorted, v_sorted,
                                   e_orig, nrm, E);

  // GCN layer 0: x(N,32) -> bufA
  lin_node<32><<<NB, TPB, 0, stream>>>(x, W0, bufB, N);
  aggregate<<<AB, TPB, 0, stream>>>(bufB, row_ptr, u_sorted, nrm, dinv, b0, bufA, N);
  // layer 1
  lin_node<64><<<NB, TPB, 0, stream>>>(bufA, W1, bufB, N);
  aggregate<<<AB, TPB, 0, stream>>>(bufB, row_ptr, u_sorted, nrm, dinv, b1, bufA, N);
  // layer 2
  lin_node<64><<<NB, TPB, 0, stream>>>(bufA, W2, bufB, N);
  aggregate<<<AB, TPB, 0, stream>>>(bufB, row_ptr, u_sorted, nrm, dinv, b2, bufA, N);

  // edge-MLP layer-1 factorization: apre = H@Wm1[0:64], bpre = H@Wm1[64:128]
  lin_ab<<<NB, TPB, 0, stream>>>(bufA, Wm1, bufB, bpre, N);

  // edge MLP in CSR order
  edge_mlp<<<EB2, TPBE, 0, stream>>>(bufB, bpre, u_sorted, v_sorted, e_orig, ef,
                                     Wm1 + 128 * 64, bm1, Wm2, bm2, Wm3, bm3, out, E);
}

// Round 4
// 708.109 us; speedup vs baseline: 1.8403x; 1.0943x over previous
//
#include <hip/hip_runtime.h>
#include <cstdint>

#define TPB 256

// ---------------------------------------------------------------------------
// EdgeGCN: 3x GCNConv (N=100k, 32->64->64->64) + per-edge MLP (136->64->32->1)
// R4: layer-0 aggregates raw x (Agg(x)@W0 == Agg(x@W0), halves its gathers);
//     edge MLP reads weights at uniform const offsets (s_load path, no LDS).
// ---------------------------------------------------------------------------

__device__ __forceinline__ void fma_row64(float zi, const float* __restrict__ wrow,
                                          float* acc) {
  const float4* w4 = (const float4*)wrow;
#pragma unroll
  for (int j4 = 0; j4 < 16; ++j4) {
    float4 w = w4[j4];
    acc[4 * j4 + 0] = fmaf(zi, w.x, acc[4 * j4 + 0]);
    acc[4 * j4 + 1] = fmaf(zi, w.y, acc[4 * j4 + 1]);
    acc[4 * j4 + 2] = fmaf(zi, w.z, acc[4 * j4 + 2]);
    acc[4 * j4 + 3] = fmaf(zi, w.w, acc[4 * j4 + 3]);
  }
}

// --- zero cnt/fill + detect int64-vs-int32 edge_index ----------------------
__global__ __launch_bounds__(TPB) void prep(int* __restrict__ cnt,
                                            int* __restrict__ fill, int n,
                                            const int* __restrict__ ei,
                                            int* __restrict__ flag) {
  int i = blockIdx.x * TPB + threadIdx.x;
  if (i < n) { cnt[i] = 0; fill[i] = 0; }
  if (blockIdx.x == 0 && threadIdx.x == 0) {
    int o = 0;
    for (int k = 0; k < 32; ++k) o |= ei[2 * k + 1];  // high words if int64
    *flag = (o == 0) ? 1 : 0;
  }
}

// --- normalize indices to int32 + count in-degree --------------------------
__global__ __launch_bounds__(TPB) void normalize_count(const int* __restrict__ ei,
                                                       const int* __restrict__ flag,
                                                       int* __restrict__ uu,
                                                       int* __restrict__ vv,
                                                       int* __restrict__ cnt, int E) {
  int e = blockIdx.x * TPB + threadIdx.x;
  if (e >= E) return;
  int u, v;
  if (*flag) {  // int64 little-endian: low word at 2*k
    u = ei[2 * (size_t)e];
    v = ei[2 * ((size_t)E + e)];
  } else {
    u = ei[e];
    v = ei[(size_t)E + e];
  }
  uu[e] = u;
  vv[e] = v;
  atomicAdd(&cnt[v], 1);
}

// exclusive scan of cnt -> row_ptr (1024 elems/block) + dinv = rsqrt(cnt+1)
__global__ __launch_bounds__(TPB) void scan1(const int* __restrict__ cnt,
                                             int* __restrict__ out,
                                             int* __restrict__ bsums,
                                             float* __restrict__ dinv, int n) {
  __shared__ int tmp[TPB];
  int tid = threadIdx.x;
  int base = blockIdx.x * 1024 + tid * 4;
  int v0 = 0, v1 = 0, v2 = 0, v3 = 0;
  if (base + 0 < n) v0 = cnt[base + 0];
  if (base + 1 < n) v1 = cnt[base + 1];
  if (base + 2 < n) v2 = cnt[base + 2];
  if (base + 3 < n) v3 = cnt[base + 3];
  if (base + 0 < n) dinv[base + 0] = rsqrtf((float)v0 + 1.0f);
  if (base + 1 < n) dinv[base + 1] = rsqrtf((float)v1 + 1.0f);
  if (base + 2 < n) dinv[base + 2] = rsqrtf((float)v2 + 1.0f);
  if (base + 3 < n) dinv[base + 3] = rsqrtf((float)v3 + 1.0f);
  int s = v0 + v1 + v2 + v3;
  tmp[tid] = s;
  __syncthreads();
  for (int off = 1; off < TPB; off <<= 1) {
    int x = (tid >= off) ? tmp[tid - off] : 0;
    __syncthreads();
    tmp[tid] += x;
    __syncthreads();
  }
  int excl = tmp[tid] - s;
  if (tid == TPB - 1) bsums[blockIdx.x] = tmp[TPB - 1];
  if (base + 0 < n) out[base + 0] = excl;
  if (base + 1 < n) out[base + 1] = excl + v0;
  if (base + 2 < n) out[base + 2] = excl + v0 + v1;
  if (base + 3 < n) out[base + 3] = excl + v0 + v1 + v2;
}

__global__ void scan2(int* __restrict__ bsums, int nb) {
  if (threadIdx.x == 0 && blockIdx.x == 0) {
    int run = 0;
    for (int i = 0; i < nb; ++i) { int t = bsums[i]; bsums[i] = run; run += t; }
  }
}

__global__ __launch_bounds__(TPB) void scan3(int* __restrict__ row_ptr,
                                             const int* __restrict__ bsums, int n,
                                             int total) {
  int i = blockIdx.x * TPB + threadIdx.x;
  if (i < n) row_ptr[i] += bsums[i >> 10];
  if (i == 0) row_ptr[n] = total;
}

// --- CSR fill: also record v and original edge id per slot -----------------
__global__ __launch_bounds__(TPB) void fill_csr(const int* __restrict__ uu,
                                                const int* __restrict__ vv,
                                                const int* __restrict__ row_ptr,
                                                int* __restrict__ fill,
                                                const float* __restrict__ dinv,
                                                int* __restrict__ u_sorted,
                                                int* __restrict__ v_sorted,
                                                int* __restrict__ e_orig,
                                                float* __restrict__ nrm, int E) {
  int e = blockIdx.x * TPB + threadIdx.x;
  if (e >= E) return;
  int u = uu[e], v = vv[e];
  int slot = row_ptr[v] + atomicAdd(&fill[v], 1);
  u_sorted[slot] = u;
  v_sorted[slot] = v;
  e_orig[slot] = e;
  nrm[slot] = dinv[u] * dinv[v];
}

// --- layer-0: aggregate raw x (32-wide). Half-wave per node-half -----------
// lane = 32*half + f; neighbors k+half; cross-half combine via shfl_xor(32).
__global__ __launch_bounds__(TPB) void aggregate32(const float* __restrict__ X,
                                                   const int* __restrict__ row_ptr,
                                                   const int* __restrict__ u_sorted,
                                                   const float* __restrict__ nrm,
                                                   const float* __restrict__ dinv,
                                                   float* __restrict__ xagg, int n) {
  int wid = (blockIdx.x * TPB + threadIdx.x) >> 6;  // node
  int lane = threadIdx.x & 63;
  int f = lane & 31;
  int half = lane >> 5;
  if (wid >= n) return;
  float dv = dinv[wid];
  float acc0 = (half == 0) ? X[(size_t)wid * 32 + f] * dv * dv : 0.f;  // self-loop
  float acc1 = 0.f;
  int rs = row_ptr[wid], re = row_ptr[wid + 1];
  for (int base = rs; base < re; base += 64) {
    int m = re - base;
    if (m > 64) m = 64;
    int uj = 0;
    float wj = 0.f;
    if (lane < m) { uj = u_sorted[base + lane]; wj = nrm[base + lane]; }
    int k = 0;
    for (; k + 3 < m; k += 4) {
      int uA = __shfl(uj, k + half), uB = __shfl(uj, k + 2 + half);
      float wA = __shfl(wj, k + half), wB = __shfl(wj, k + 2 + half);
      acc0 = fmaf(X[(size_t)uA * 32 + f], wA, acc0);
      acc1 = fmaf(X[(size_t)uB * 32 + f], wB, acc1);
    }
    for (; k < m; k += 2) {
      if (k + half < m) {
        int uA = __shfl(uj, k + half);
        float wA = __shfl(wj, k + half);
        acc0 = fmaf(X[(size_t)uA * 32 + f], wA, acc0);
      }
    }
  }
  float tot = acc0 + acc1;
  tot += __shfl_xor(tot, 32);
  if (half == 0) xagg[(size_t)wid * 32 + f] = tot;
}

// --- layer-0 linear with bias+relu: bufA = relu(xagg @ W0 + b0) ------------
__global__ __launch_bounds__(TPB) void lin32_br(const float* __restrict__ A,
                                                const float* __restrict__ W,
                                                const float* __restrict__ bias,
                                                float* __restrict__ B, int n) {
  __shared__ __align__(16) float Ws[32 * 64];
  __shared__ float bs[64];
  int tid = threadIdx.x;
  for (int i = tid; i < 32 * 64; i += TPB) Ws[i] = W[i];
  if (tid < 64) bs[tid] = bias[tid];
  __syncthreads();
  int node = blockIdx.x * TPB + tid;
  if (node >= n) return;
  const float4* a4 = (const float4*)(A + (size_t)node * 32);
  float acc[64];
#pragma unroll
  for (int j = 0; j < 64; ++j) acc[j] = bs[j];
  for (int i4 = 0; i4 < 8; ++i4) {
    float4 z = a4[i4];
    fma_row64(z.x, &Ws[(4 * i4 + 0) * 64], acc);
    fma_row64(z.y, &Ws[(4 * i4 + 1) * 64], acc);
    fma_row64(z.z, &Ws[(4 * i4 + 2) * 64], acc);
    fma_row64(z.w, &Ws[(4 * i4 + 3) * 64], acc);
  }
  float4* b4 = (float4*)(B + (size_t)node * 64);
#pragma unroll
  for (int j4 = 0; j4 < 16; ++j4)
    b4[j4] = make_float4(fmaxf(acc[4 * j4 + 0], 0.f), fmaxf(acc[4 * j4 + 1], 0.f),
                         fmaxf(acc[4 * j4 + 2], 0.f), fmaxf(acc[4 * j4 + 3], 0.f));
}

// --- node linear (64 -> 64), no bias/relu ----------------------------------
__global__ __launch_bounds__(TPB) void lin_node64(const float* __restrict__ A,
                                                  const float* __restrict__ W,
                                                  float* __restrict__ B, int n) {
  __shared__ __align__(16) float Ws[64 * 64];
  int tid = threadIdx.x;
  for (int i = tid; i < 64 * 64; i += TPB) Ws[i] = W[i];
  __syncthreads();
  int node = blockIdx.x * TPB + tid;
  if (node >= n) return;
  const float4* a4 = (const float4*)(A + (size_t)node * 64);
  float acc[64];
#pragma unroll
  for (int j = 0; j < 64; ++j) acc[j] = 0.f;
  for (int i4 = 0; i4 < 16; ++i4) {
    float4 z = a4[i4];
    fma_row64(z.x, &Ws[(4 * i4 + 0) * 64], acc);
    fma_row64(z.y, &Ws[(4 * i4 + 1) * 64], acc);
    fma_row64(z.z, &Ws[(4 * i4 + 2) * 64], acc);
    fma_row64(z.w, &Ws[(4 * i4 + 3) * 64], acc);
  }
  float4* b4 = (float4*)(B + (size_t)node * 64);
#pragma unroll
  for (int j4 = 0; j4 < 16; ++j4)
    b4[j4] = make_float4(acc[4 * j4 + 0], acc[4 * j4 + 1], acc[4 * j4 + 2],
                         acc[4 * j4 + 3]);
}

// --- fused apre/bpre: apre = A@W[0:64], bpre = A@W[64:128] -----------------
__global__ __launch_bounds__(TPB) void lin_ab(const float* __restrict__ A,
                                              const float* __restrict__ W,
                                              float* __restrict__ apre,
                                              float* __restrict__ bpre, int n) {
  __shared__ __align__(16) float Ws[128 * 64];  // 32 KB
  int tid = threadIdx.x;
  for (int i = tid; i < 128 * 64; i += TPB) Ws[i] = W[i];
  __syncthreads();
  int node = blockIdx.x * TPB + tid;
  if (node >= n) return;
  const float4* a4 = (const float4*)(A + (size_t)node * 64);
  float acc[64];
#pragma unroll
  for (int j = 0; j < 64; ++j) acc[j] = 0.f;
  for (int i4 = 0; i4 < 16; ++i4) {
    float4 z = a4[i4];
    fma_row64(z.x, &Ws[(4 * i4 + 0) * 64], acc);
    fma_row64(z.y, &Ws[(4 * i4 + 1) * 64], acc);
    fma_row64(z.z, &Ws[(4 * i4 + 2) * 64], acc);
    fma_row64(z.w, &Ws[(4 * i4 + 3) * 64], acc);
  }
  float4* o4 = (float4*)(apre + (size_t)node * 64);
#pragma unroll
  for (int j4 = 0; j4 < 16; ++j4)
    o4[j4] = make_float4(acc[4 * j4 + 0], acc[4 * j4 + 1], acc[4 * j4 + 2],
                         acc[4 * j4 + 3]);
#pragma unroll
  for (int j = 0; j < 64; ++j) acc[j] = 0.f;
  for (int i4 = 0; i4 < 16; ++i4) {
    float4 z = a4[i4];  // L1-hot reread
    fma_row64(z.x, &Ws[(64 + 4 * i4 + 0) * 64], acc);
    fma_row64(z.y, &Ws[(64 + 4 * i4 + 1) * 64], acc);
    fma_row64(z.z, &Ws[(64 + 4 * i4 + 2) * 64], acc);
    fma_row64(z.w, &Ws[(64 + 4 * i4 + 3) * 64], acc);
  }
  o4 = (float4*)(bpre + (size_t)node * 64);
#pragma unroll
  for (int j4 = 0; j4 < 16; ++j4)
    o4[j4] = make_float4(acc[4 * j4 + 0], acc[4 * j4 + 1], acc[4 * j4 + 2],
                         acc[4 * j4 + 3]);
}

// --- aggregation (64-wide): wave per node; shfl broadcast + 4-deep ILP -----
__global__ __launch_bounds__(TPB) void aggregate(const float* __restrict__ B,
                                                 const int* __restrict__ row_ptr,
                                                 const int* __restrict__ u_sorted,
                                                 const float* __restrict__ nrm,
                                                 const float* __restrict__ dinv,
                                                 const float* __restrict__ bias,
                                                 float* __restrict__ A, int n) {
  int wid = (blockIdx.x * TPB + threadIdx.x) >> 6;  // node
  int lane = threadIdx.x & 63;                      // feature
  if (wid >= n) return;
  float dv = dinv[wid];
  float acc0 = B[(size_t)wid * 64 + lane] * dv * dv;  // self-loop
  float acc1 = 0.f, acc2 = 0.f, acc3 = 0.f;
  int rs = row_ptr[wid], re = row_ptr[wid + 1];
  for (int base = rs; base < re; base += 64) {
    int m = re - base;
    if (m > 64) m = 64;
    int uj = 0;
    float wj = 0.f;
    if (lane < m) { uj = u_sorted[base + lane]; wj = nrm[base + lane]; }
    int k = 0;
    for (; k + 3 < m; k += 4) {
      int u0 = __shfl(uj, k), u1 = __shfl(uj, k + 1);
      int u2 = __shfl(uj, k + 2), u3 = __shfl(uj, k + 3);
      float w0 = __shfl(wj, k), w1 = __shfl(wj, k + 1);
      float w2 = __shfl(wj, k + 2), w3 = __shfl(wj, k + 3);
      acc0 = fmaf(B[(size_t)u0 * 64 + lane], w0, acc0);
      acc1 = fmaf(B[(size_t)u1 * 64 + lane], w1, acc1);
      acc2 = fmaf(B[(size_t)u2 * 64 + lane], w2, acc2);
      acc3 = fmaf(B[(size_t)u3 * 64 + lane], w3, acc3);
    }
    for (; k < m; ++k) {
      int u0 = __shfl(uj, k);
      float w0 = __shfl(wj, k);
      acc0 = fmaf(B[(size_t)u0 * 64 + lane], w0, acc0);
    }
  }
  A[(size_t)wid * 64 + lane] =
      fmaxf((acc0 + acc1) + (acc2 + acc3) + bias[lane], 0.f);
}

// --- edge MLP, CSR order, weights via uniform (scalar) loads ---------------
// acc = apre[u] + bpre[v] + ef[e] @ Wm1[128:136] + bm1; relu; 64->32; relu; ->1
__global__ __launch_bounds__(TPB) void edge_mlp(
    const float* __restrict__ apre, const float* __restrict__ bpre,
    const int* __restrict__ u_sorted, const int* __restrict__ v_sorted,
    const int* __restrict__ e_orig, const float* __restrict__ EF,
    const float* __restrict__ W1e,  // Wm1 + 128*64
    const float* __restrict__ bm1, const float* __restrict__ Wm2,
    const float* __restrict__ bm2, const float* __restrict__ Wm3,
    const float* __restrict__ bm3, float* __restrict__ out, int E) {
  int t = blockIdx.x * TPB + threadIdx.x;
  if (t >= E) return;
  int u = u_sorted[t], v = v_sorted[t], e = e_orig[t];
  const float4* a4 = (const float4*)(apre + (size_t)u * 64);
  const float4* b4 = (const float4*)(bpre + (size_t)v * 64);  // wave-shared row
  const float4* ef4 = (const float4*)(EF + (size_t)e * 8);

  float4 z0 = ef4[0], z1 = ef4[1];
  float acc[64];
#pragma unroll
  for (int j = 0; j < 64; ++j) acc[j] = bm1[j];  // uniform -> s_load
  fma_row64(z0.x, W1e + 0 * 64, acc);
  fma_row64(z0.y, W1e + 1 * 64, acc);
  fma_row64(z0.z, W1e + 2 * 64, acc);
  fma_row64(z0.w, W1e + 3 * 64, acc);
  fma_row64(z1.x, W1e + 4 * 64, acc);
  fma_row64(z1.y, W1e + 5 * 64, acc);
  fma_row64(z1.z, W1e + 6 * 64, acc);
  fma_row64(z1.w, W1e + 7 * 64, acc);

#pragma unroll
  for (int i4 = 0; i4 < 16; ++i4) {
    float4 za = a4[i4];
    float4 zb = b4[i4];
    acc[4 * i4 + 0] += za.x + zb.x;
    acc[4 * i4 + 1] += za.y + zb.y;
    acc[4 * i4 + 2] += za.z + zb.z;
    acc[4 * i4 + 3] += za.w + zb.w;
  }

  // layer 2: 64 -> 32, relu on inputs; weights uniform -> s_load
  float z2[32];
#pragma unroll
  for (int j = 0; j < 32; ++j) z2[j] = bm2[j];
#pragma unroll
  for (int i = 0; i < 64; ++i) {
    float zi = fmaxf(acc[i], 0.f);
    const float4* w4 = (const float4*)(Wm2 + i * 32);
#pragma unroll
    for (int j4 = 0; j4 < 8; ++j4) {
      float4 w = w4[j4];
      z2[4 * j4 + 0] = fmaf(zi, w.x, z2[4 * j4 + 0]);
      z2[4 * j4 + 1] = fmaf(zi, w.y, z2[4 * j4 + 1]);
      z2[4 * j4 + 2] = fmaf(zi, w.z, z2[4 * j4 + 2]);
      z2[4 * j4 + 3] = fmaf(zi, w.w, z2[4 * j4 + 3]);
    }
  }
  // layer 3: 32 -> 1
  float o = bm3[0];
#pragma unroll
  for (int i = 0; i < 32; ++i) o = fmaf(fmaxf(z2[i], 0.f), Wm3[i], o);
  out[e] = o;
}

// ---------------------------------------------------------------------------
extern "C" void kernel_launch(void* const* d_in, const int* in_sizes, int n_in,
                              void* d_out, int out_size, void* d_ws, size_t ws_size,
                              hipStream_t stream) {
  const float* x   = (const float*)d_in[0];
  const int*   ei  = (const int*)d_in[1];
  const float* ef  = (const float*)d_in[2];
  const float* W0  = (const float*)d_in[3];
  const float* b0  = (const float*)d_in[4];
  const float* W1  = (const float*)d_in[5];
  const float* b1  = (const float*)d_in[6];
  const float* W2  = (const float*)d_in[7];
  const float* b2  = (const float*)d_in[8];
  const float* Wm1 = (const float*)d_in[9];
  const float* bm1 = (const float*)d_in[10];
  const float* Wm2 = (const float*)d_in[11];
  const float* bm2 = (const float*)d_in[12];
  const float* Wm3 = (const float*)d_in[13];
  const float* bm3 = (const float*)d_in[14];
  float* out = (float*)d_out;

  const int N = in_sizes[0] / 32;
  const int E = in_sizes[2] / 8;

  // workspace carve (256B aligned)
  char* p = (char*)d_ws;
  auto carve = [&](size_t bytes) {
    void* r = (void*)p;
    p += ((bytes + 255) / 256) * 256;
    return r;
  };
  int*   cnt      = (int*)carve((size_t)N * 4);
  int*   row_ptr  = (int*)carve((size_t)(N + 1) * 4);
  int*   fill     = (int*)carve((size_t)N * 4);
  float* dinv     = (float*)carve((size_t)N * 4);
  int*   bsums    = (int*)carve(4096);
  int*   flag     = (int*)carve(256);
  int*   u_sorted = (int*)carve((size_t)E * 4);
  int*   v_sorted = (int*)carve((size_t)E * 4);
  int*   e_orig   = (int*)carve((size_t)E * 4);
  float* nrm      = (float*)carve((size_t)E * 4);
  float* bufB     = (float*)carve((size_t)N * 64 * 4);  // scratch/apre; head = xagg
  float* bpre     = (float*)carve((size_t)N * 64 * 4);  // bpre
  float* bufA     = (float*)carve((size_t)N * 64 * 4);  // H; head doubles as uu/vv
  if ((size_t)(p - (char*)d_ws) > ws_size) return;  // ws too small: bail loudly

  // uu/vv alias head of bufA (dead after fill_csr, before bufA written)
  int* uu = (int*)bufA;
  int* vv = uu + E;
  // xagg aliases head of bufB (dead before bufB written by lin_node64)
  float* xagg = bufB;

  const int EB = (E + TPB - 1) / TPB;
  const int NB = (N + TPB - 1) / TPB;
  const int SB = (N + 1023) / 1024;
  const int AB = (N + 3) / 4;  // 4 waves/block, wave per node

  prep<<<NB, TPB, 0, stream>>>(cnt, fill, N, ei, flag);
  normalize_count<<<EB, TPB, 0, stream>>>(ei, flag, uu, vv, cnt, E);
  scan1<<<SB, TPB, 0, stream>>>(cnt, row_ptr, bsums, dinv, N);
  scan2<<<1, 64, 0, stream>>>(bsums, SB);
  scan3<<<NB, TPB, 0, stream>>>(row_ptr, bsums, N, E);
  fill_csr<<<EB, TPB, 0, stream>>>(uu, vv, row_ptr, fill, dinv, u_sorted, v_sorted,
                                   e_orig, nrm, E);

  // GCN layer 0: aggregate raw x (32-wide), then lin+bias+relu -> bufA
  aggregate32<<<AB, TPB, 0, stream>>>(x, row_ptr, u_sorted, nrm, dinv, xagg, N);
  lin32_br<<<NB, TPB, 0, stream>>>(xagg, W0, b0, bufA, N);
  // layer 1
  lin_node64<<<NB, TPB, 0, stream>>>(bufA, W1, bufB, N);
  aggregate<<<AB, TPB, 0, stream>>>(bufB, row_ptr, u_sorted, nrm, dinv, b1, bufA, N);
  // layer 2
  lin_node64<<<NB, TPB, 0, stream>>>(bufA, W2, bufB, N);
  aggregate<<<AB, TPB, 0, stream>>>(bufB, row_ptr, u_sorted, nrm, dinv, b2, bufA, N);

  // edge-MLP layer-1 factorization: apre = H@Wm1[0:64], bpre = H@Wm1[64:128]
  lin_ab<<<NB, TPB, 0, stream>>>(bufA, Wm1, bufB, bpre, N);

  // edge MLP in CSR order (no LDS; weights via scalar loads)
  edge_mlp<<<EB, TPB, 0, stream>>>(bufB, bpre, u_sorted, v_sorted, e_orig, ef,
                                   Wm1 + 128 * 64, bm1, Wm2, bm2, Wm3, bm3, out, E);
}